// Round 10
// baseline (97.669 us; speedup 1.0000x reference)
//
#include <hip/hip_runtime.h>
#include <hip/hip_bf16.h>

// out = softmax((X Wq + bq)(X Wk + bk)^T / 8) (X Wv + bv) Wo + bo
// All prune/straight-through ops in the reference are value-wise identity.
//
// Pipeline (all bf16 MFMA 16x16x32, fp32 accum):
//   k_prep: fused {hs->bf16 A [4736][768] w/ zero pad | W^T bf16 x4 | kh/vt pad zero}
//   k_qkv : fused QKV GEMM, 256x256 tile, 512 thr / 8 waves (2m x 4n), BK=64,
//           4-phase-per-K-tile schedule (8-phase template at 2-tile granularity):
//           per phase {ds_read subtile || stage} -> bar -> lgkm0 -> 16 MFMA -> bar,
//           stages issued 4 phases before the vmcnt(0) drain. LDS 128KB dbuf.
//           Chunked LDS-staged coalesced epilogue (V transposed).
//   k_attn: flash attention, QBLK=128 (2 q-frags/wave), K/V double-buffered
//           gload_lds (counted vmcnt), XCD-pinned grid (bh%8), exp2 softmax,
//           MFMA row-sum, setprio (round-6 proven version)
//   k_gemm: out-proj ctx@Wo+bo -> fp32 (round-6 proven 128^2 version, mode 3)

#define B_ 8
#define S_ 577
#define H_ 768
#define NH_ 12
#define HD_ 64
#define M_ (B_*S_)     /* 4616 */
#define MPAD 4736      /* 37*128 */
#define BH_ (B_*NH_)   /* 96 */
#define SKPAD 640      /* padded key count */
#define LTS 136        /* padded LDS row stride (128-tile epilogue) */
#define LTS2 264       /* padded LDS row stride (256-tile epilogue chunks) */

typedef __attribute__((ext_vector_type(8))) short short8;
typedef __attribute__((ext_vector_type(4))) short s16x4;
typedef __attribute__((ext_vector_type(4))) float f32x4;

__device__ inline unsigned short f2bf(float f){
    unsigned int u = __float_as_uint(f);
    u = u + 0x7fffu + ((u>>16)&1u);     // round-to-nearest-even
    return (unsigned short)(u>>16);
}

__device__ inline void gload_lds16(const short* g, short* l){
    __builtin_amdgcn_global_load_lds((const __attribute__((address_space(1))) void*)g,
                                     (__attribute__((address_space(3))) void*)l, 16, 0, 0);
}

// fused prep: blocks [0,1776) cvt | [1776,2352) wt | [2352,2733) pad
__global__ __launch_bounds__(256) void k_prep(
    const float* __restrict__ hs, short* __restrict__ abf,
    const float* __restrict__ Wq, const float* __restrict__ Wk,
    const float* __restrict__ Wv, const float* __restrict__ Wo,
    short* __restrict__ Tq, short* __restrict__ Tk,
    short* __restrict__ Tv, short* __restrict__ To,
    short* __restrict__ kh, short* __restrict__ vt)
{
    const int bid = blockIdx.x, t = threadIdx.x;
    if(bid < 1776){
        int i = bid*256 + t;
        if(bid >= 1731){ *(short8*)(abf + (size_t)i*8) = (short8){}; return; }
        const float4* p = (const float4*)(hs + (size_t)i*8);
        float4 a = p[0], b = p[1];
        short8 v;
        v[0]=(short)f2bf(a.x); v[1]=(short)f2bf(a.y); v[2]=(short)f2bf(a.z); v[3]=(short)f2bf(a.w);
        v[4]=(short)f2bf(b.x); v[5]=(short)f2bf(b.y); v[6]=(short)f2bf(b.z); v[7]=(short)f2bf(b.w);
        *(short8*)(abf + (size_t)i*8) = v;
    } else if(bid < 2352){
        int zidx = bid - 1776;
        int z = zidx & 3, rem = zidx >> 2;
        int kx = rem % 12, ny = rem / 12;
        const float* W = z==0?Wq: z==1?Wk: z==2?Wv:Wo;
        short*       T = z==0?Tq: z==1?Tk: z==2?Tv:To;
        __shared__ float lds[64][65];
        int k0 = kx*64, n0 = ny*64;
        for(int i=0;i<4;i++){
            int row = i*16 + (t>>4);
            int col = (t&15)*4;
            float4 v = *(const float4*)&W[(k0+row)*768 + n0 + col];
            lds[row][col]=v.x; lds[row][col+1]=v.y; lds[row][col+2]=v.z; lds[row][col+3]=v.w;
        }
        __syncthreads();
        for(int i=0;i<4;i++){
            int n = i*16 + (t>>4);
            int k4 = (t&15)*4;
            for(int j=0;j<4;j++)
                T[(n0+n)*768 + k0 + k4 + j] = (short)f2bf(lds[k4+j][n]);
        }
    } else {
        int tid = (bid-2352)*256 + t;
        short8 z = {};
        if(tid < 48384){
            int row_id = tid>>3, ch = tid&7;
            int bh = row_id/63, r = row_id - bh*63;
            *(short8*)&kh[((size_t)bh*SKPAD + 577 + r)*64 + ch*8] = z;
        } else if(tid < 97536){
            int j = tid - 48384;
            int row_id = j>>3, ch = j&7;
            int bh = row_id>>6, d = row_id&63;
            *(short8*)&vt[((size_t)bh*64 + d)*SKPAD + 576 + ch*8] = z;
        }
    }
}

// ---------------- fused QKV: 256x256 tile, 8 waves, 4-phase K-loop ------------
__global__ __launch_bounds__(512) void k_qkv(
    const short* __restrict__ A, const short* __restrict__ T,
    const float* __restrict__ b0, const float* __restrict__ b1, const float* __restrict__ b2,
    short* __restrict__ oq, short* __restrict__ ok, short* __restrict__ ovt)
{
    __shared__ short sh[65536];   // 128KB: A slots [0,32768), B slots [32768,65536)
    const int t = threadIdx.x;

    // bijective XCD-chunked swizzle, NT=9 n-tiles
    const int nwg = gridDim.x;
    const int q8 = nwg>>3, r8 = nwg&7;
    const int xcd = blockIdx.x&7, cidx = blockIdx.x>>3;
    const int wg = (xcd<r8 ? xcd*(q8+1) : r8*(q8+1) + (xcd-r8)*q8) + cidx;
    const int mt = wg/9, nt9 = wg - mt*9;
    const int m0 = mt*256, n0 = nt9*256;
    const int seg = n0/768;
    const float* bias = (seg==0?b0: seg==1?b1:b2);
    const int nlb = n0 - seg*768;

    const int w = t>>6, lane = t&63, g = lane>>4, c = lane&15;
    const int wm = w>>2, wn = w&3;       // wave tile: rows wm*128.., cols wn*64..

    // staging: thread covers srow = t>>3 within each 64-row inst block, chunk t&7
    const int srow = t>>3, sch = t&7;
    const int sx = (sch ^ (srow&7))*8;   // pre-swizzled source chunk (shorts)
    const short* pa[2][2]; const short* pb[2][2];
    #pragma unroll
    for(int hf=0; hf<2; hf++)
        #pragma unroll
        for(int i=0;i<2;i++){
            int rga = m0 + hf*128 + i*64 + srow;
            if(rga > 4735) rga = 4735;              // clamp into zero-pad rows
            pa[hf][i] = A + (size_t)rga*768 + sx;
            pb[hf][i] = T + (size_t)(n0 + hf*128 + i*64 + srow)*768 + sx;
        }
    const int dof = srow*64 + sch*8;

    f32x4 acc[8][4] = {};

    #define STAGE(tt) { int pS = ((tt)&1)*16384; int kof = (tt)*64;              \
        _Pragma("unroll") for(int hf=0; hf<2; hf++){                             \
            _Pragma("unroll") for(int i=0;i<2;i++){                              \
                gload_lds16(pa[hf][i] + kof, &sh[pS + hf*8192 + i*4096 + dof]);  \
                gload_lds16(pb[hf][i] + kof, &sh[32768 + pS + hf*8192 + i*4096 + dof]); } } }

    // prologue: tile 0 into slot 0
    STAGE(0);
    asm volatile("s_waitcnt vmcnt(0)" ::: "memory");
    __builtin_amdgcn_s_barrier();
    asm volatile("" ::: "memory");

    for(int kt=0; kt<12; kt++){
        const int p = (kt&1)*16384;
        const short* LA = &sh[p + wm*8192];
        const short* LB = &sh[32768 + p + (wn>>1)*8192];
        const int brow0 = (wn&1)*64;

        short8 af[4][2], af2[4][2], bfv[4][2];
        // ---- phase 1: A m0-3 + B n0-1 reads; stage next tile ----
        #pragma unroll
        for(int mi=0; mi<4; mi++){
            int rih = mi*16 + c, rx = (rih&7)<<3;
            af[mi][0] = *(const short8*)&LA[rih*64 + ((g*8) ^ rx)];
            af[mi][1] = *(const short8*)&LA[rih*64 + ((32+g*8) ^ rx)];
        }
        #pragma unroll
        for(int ni=0; ni<2; ni++){
            int rih = brow0 + ni*16 + c, rx = (rih&7)<<3;
            bfv[ni][0] = *(const short8*)&LB[rih*64 + ((g*8) ^ rx)];
            bfv[ni][1] = *(const short8*)&LB[rih*64 + ((32+g*8) ^ rx)];
        }
        if(kt < 11) STAGE(kt+1);
        __builtin_amdgcn_s_barrier();
        asm volatile("s_waitcnt lgkmcnt(0)" ::: "memory");
        __builtin_amdgcn_s_setprio(1);
        #pragma unroll
        for(int mi=0; mi<4; mi++)
            #pragma unroll
            for(int ni=0; ni<2; ni++){
                acc[mi][ni] = __builtin_amdgcn_mfma_f32_16x16x32_bf16(af[mi][0], bfv[ni][0], acc[mi][ni], 0,0,0);
                acc[mi][ni] = __builtin_amdgcn_mfma_f32_16x16x32_bf16(af[mi][1], bfv[ni][1], acc[mi][ni], 0,0,0);
            }
        __builtin_amdgcn_s_setprio(0);
        __builtin_amdgcn_s_barrier();
        asm volatile("" ::: "memory");

        // ---- phase 2: B n2-3 reads ----
        #pragma unroll
        for(int ni=2; ni<4; ni++){
            int rih = brow0 + ni*16 + c, rx = (rih&7)<<3;
            bfv[ni][0] = *(const short8*)&LB[rih*64 + ((g*8) ^ rx)];
            bfv[ni][1] = *(const short8*)&LB[rih*64 + ((32+g*8) ^ rx)];
        }
        __builtin_amdgcn_s_barrier();
        asm volatile("s_waitcnt lgkmcnt(0)" ::: "memory");
        __builtin_amdgcn_s_setprio(1);
        #pragma unroll
        for(int mi=0; mi<4; mi++)
            #pragma unroll
            for(int ni=2; ni<4; ni++){
                acc[mi][ni] = __builtin_amdgcn_mfma_f32_16x16x32_bf16(af[mi][0], bfv[ni][0], acc[mi][ni], 0,0,0);
                acc[mi][ni] = __builtin_amdgcn_mfma_f32_16x16x32_bf16(af[mi][1], bfv[ni][1], acc[mi][ni], 0,0,0);
            }
        __builtin_amdgcn_s_setprio(0);
        __builtin_amdgcn_s_barrier();
        asm volatile("" ::: "memory");

        // ---- phase 3: A m4-7 reads ----
        #pragma unroll
        for(int mi=0; mi<4; mi++){
            int rih = 64 + mi*16 + c, rx = (rih&7)<<3;
            af2[mi][0] = *(const short8*)&LA[rih*64 + ((g*8) ^ rx)];
            af2[mi][1] = *(const short8*)&LA[rih*64 + ((32+g*8) ^ rx)];
        }
        __builtin_amdgcn_s_barrier();
        asm volatile("s_waitcnt lgkmcnt(0)" ::: "memory");
        __builtin_amdgcn_s_setprio(1);
        #pragma unroll
        for(int mi=0; mi<4; mi++)
            #pragma unroll
            for(int ni=0; ni<2; ni++){
                acc[4+mi][ni] = __builtin_amdgcn_mfma_f32_16x16x32_bf16(af2[mi][0], bfv[ni][0], acc[4+mi][ni], 0,0,0);
                acc[4+mi][ni] = __builtin_amdgcn_mfma_f32_16x16x32_bf16(af2[mi][1], bfv[ni][1], acc[4+mi][ni], 0,0,0);
            }
        __builtin_amdgcn_s_setprio(0);
        __builtin_amdgcn_s_barrier();
        asm volatile("" ::: "memory");

        // ---- phase 4: compute; drain next tile's stages; barrier ----
        __builtin_amdgcn_s_setprio(1);
        #pragma unroll
        for(int mi=0; mi<4; mi++)
            #pragma unroll
            for(int ni=2; ni<4; ni++){
                acc[4+mi][ni] = __builtin_amdgcn_mfma_f32_16x16x32_bf16(af2[mi][0], bfv[ni][0], acc[4+mi][ni], 0,0,0);
                acc[4+mi][ni] = __builtin_amdgcn_mfma_f32_16x16x32_bf16(af2[mi][1], bfv[ni][1], acc[4+mi][ni], 0,0,0);
            }
        __builtin_amdgcn_s_setprio(0);
        asm volatile("s_waitcnt vmcnt(0)" ::: "memory");
        __builtin_amdgcn_s_barrier();
        asm volatile("" ::: "memory");
    }
    #undef STAGE

    // ---------------- epilogue: chunked LDS-staged coalesced stores ----------
    if(seg==2){
        // V: transposed [n][m] chunks of 128 n-rows
        #pragma unroll
        for(int cch=0; cch<2; cch++){
            if((wn>>1) == cch){
                #pragma unroll
                for(int mi=0; mi<8; mi++)
                    #pragma unroll
                    for(int ni=0; ni<4; ni++){
                        int nc = (wn&1)*64 + ni*16 + c;
                        float bv = bias[nlb + cch*128 + nc];
                        s16x4 pk;
                        #pragma unroll
                        for(int r=0;r<4;r++) pk[r] = (short)f2bf(acc[mi][ni][r] + bv);
                        int ml0 = wm*128 + mi*16 + g*4;
                        *(s16x4*)&sh[nc*LTS2 + ml0] = pk;
                    }
            }
            __syncthreads();
            #pragma unroll
            for(int i=0;i<8;i++){
                int idx = i*512 + t;
                int rp = idx>>5, ch = idx&31;
                short8 v8 = *(const short8*)&sh[rp*LTS2 + ch*8];
                int nl = nlb + cch*128 + rp, hh = nl>>6, dd = nl&63;
                int mg = m0 + ch*8;
                if(mg < M_){
                    int bb = mg/S_, s0 = mg - bb*S_;
                    if(s0+7 < S_ && mg+7 < M_){
                        *(short8*)&ovt[(((size_t)bb*NH_+hh)*HD_+dd)*SKPAD + s0] = v8;
                    } else {
                        for(int j=0;j<8;j++){
                            int m=mg+j;
                            if(m<M_){ int bj=m/S_, sj=m-bj*S_;
                                ovt[(((size_t)bj*NH_+hh)*HD_+dd)*SKPAD+sj]=v8[j]; }
                        }
                    }
                }
            }
            __syncthreads();
        }
    } else {
        // Q/K: row-major [m][n] chunks of 128 m-rows
        #pragma unroll
        for(int cch=0; cch<2; cch++){
            if(wm == cch){
                #pragma unroll
                for(int mi=0; mi<8; mi++)
                    #pragma unroll
                    for(int ni=0; ni<4; ni++){
                        int nl_ = wn*64 + ni*16 + c;
                        float bv = bias[nlb + nl_];
                        #pragma unroll
                        for(int r=0;r<4;r++){
                            int ml = mi*16 + g*4 + r;
                            sh[ml*LTS2 + nl_] = (short)f2bf(acc[mi][ni][r] + bv);
                        }
                    }
            }
            __syncthreads();
            #pragma unroll
            for(int i=0;i<8;i++){
                int idx = i*512 + t;
                int rp = idx>>5, ch = idx&31;
                short8 v8 = *(const short8*)&sh[rp*LTS2 + ch*8];
                int m = m0 + cch*128 + rp;
                if(m < M_){
                    int bb = m/S_, ss = m - bb*S_;
                    int nl = nlb + ch*8, hh = nl>>6, dd = nl&63;
                    if(seg==1) *(short8*)&ok[(((size_t)bb*NH_+hh)*SKPAD + ss)*HD_ + dd] = v8;
                    else       *(short8*)&oq[(((size_t)bb*NH_+hh)*S_   + ss)*HD_ + dd] = v8;
                }
            }
            __syncthreads();
        }
    }
}

// out-proj GEMM (round-6 proven): 128x128 tile, 512 thr, dbuf vmcnt(4), mode 3
__global__ __launch_bounds__(512) void k_gemm(
    const short* __restrict__ A, const short* __restrict__ T,
    const float* __restrict__ b0,
    float* __restrict__ of, int NT)
{
    __shared__ short sh[32768];
    const int t = threadIdx.x;

    const int nwg = gridDim.x;
    const int q8 = nwg>>3, r8 = nwg&7;
    const int xcd = blockIdx.x&7, cidx = blockIdx.x>>3;
    const int wg = (xcd<r8 ? xcd*(q8+1) : r8*(q8+1) + (xcd-r8)*q8) + cidx;
    const int mt = wg/NT, ntile = wg - mt*NT;
    const int m0 = mt*128, n0 = ntile*128;
    const float* bias = b0;

    const int w = t>>6, lane = t&63, g = lane>>4, c = lane&15;
    const int wm = w>>1, wn = w&1;

    const int lrow = lane>>3;
    const int lcol = ((lane&7) ^ lrow) * 8;
    const short* pa = A + (size_t)(m0 + w*8 + lrow)*768 + lcol;
    const short* pb = T + (size_t)(n0 + w*8 + lrow)*768 + lcol;

    f32x4 acc[2][4] = {};

    #pragma unroll
    for(int i=0;i<2;i++){
        gload_lds16(pa + (size_t)(i*64)*768, &sh[(i*64 + w*8)*64]);
        gload_lds16(pb + (size_t)(i*64)*768, &sh[8192 + (i*64 + w*8)*64]);
    }
    int bb = 0;
    for(int kk=0; kk<12; kk++){
        if(kk<11){
            short* dstA = &sh[(bb^1)*16384];
            short* dstB = dstA + 8192;
            #pragma unroll
            for(int i=0;i<2;i++){
                gload_lds16(pa + (size_t)(i*64)*768 + (kk+1)*64, &dstA[(i*64 + w*8)*64]);
                gload_lds16(pb + (size_t)(i*64)*768 + (kk+1)*64, &dstB[(i*64 + w*8)*64]);
            }
            asm volatile("s_waitcnt vmcnt(4)" ::: "memory");
        } else {
            asm volatile("s_waitcnt vmcnt(0)" ::: "memory");
        }
        __builtin_amdgcn_s_barrier();
        asm volatile("" ::: "memory");

        const short* LA = &sh[bb*16384];
        const short* LB = LA + 8192;
        short8 af[2][2], bfv[4][2];
        #pragma unroll
        for(int mi=0; mi<2; mi++){
            int row = wm*32 + mi*16 + c;
            int rx = (row&7)<<3;
            af[mi][0] = *(const short8*)&LA[row*64 + ((g*8) ^ rx)];
            af[mi][1] = *(const short8*)&LA[row*64 + ((32 + g*8) ^ rx)];
        }
        #pragma unroll
        for(int ni=0; ni<4; ni++){
            int row = wn*64 + ni*16 + c;
            int rx = (row&7)<<3;
            bfv[ni][0] = *(const short8*)&LB[row*64 + ((g*8) ^ rx)];
            bfv[ni][1] = *(const short8*)&LB[row*64 + ((32 + g*8) ^ rx)];
        }
        __builtin_amdgcn_s_setprio(1);
        #pragma unroll
        for(int mi=0; mi<2; mi++)
            #pragma unroll
            for(int ni=0; ni<4; ni++){
                acc[mi][ni] = __builtin_amdgcn_mfma_f32_16x16x32_bf16(af[mi][0], bfv[ni][0], acc[mi][ni], 0,0,0);
                acc[mi][ni] = __builtin_amdgcn_mfma_f32_16x16x32_bf16(af[mi][1], bfv[ni][1], acc[mi][ni], 0,0,0);
            }
        __builtin_amdgcn_s_setprio(0);
        asm volatile("s_waitcnt lgkmcnt(0)" ::: "memory");
        __builtin_amdgcn_s_barrier();
        asm volatile("" ::: "memory");
        bb ^= 1;
    }

    #pragma unroll
    for(int mi=0; mi<2; mi++) for(int ni=0; ni<4; ni++){
        #pragma unroll
        for(int r=0; r<4; r++){
            int m = m0 + wm*32 + mi*16 + g*4 + r;
            int n = n0 + wn*64 + ni*16 + c;
            if(m >= M_) continue;
            of[(size_t)m*768 + n] = acc[mi][ni][r] + bias[n];
        }
    }
}

// flash attention (round-6 proven): QBLK=128, K/V dbuf counted vmcnt, setprio
__global__ __launch_bounds__(256) void k_attn(
    const short* __restrict__ qh, const short* __restrict__ kh, const short* __restrict__ vt,
    short* __restrict__ ctx)
{
    __shared__ short lK[2][64*64], lV[2][64*64], lP[4*2048];
    const int t = threadIdx.x;
    const int w = t>>6, lane = t&63, g = lane>>4, c = lane&15;
    const int bh = blockIdx.x, b = bh/NH_, h = bh%NH_;
    const int q0 = blockIdx.y*128;

    #pragma unroll
    for(int i=0;i<4;i++){
        int row = i*8 + (lane>>3);
        int e8 = (lane&7)*8;
        int s = q0 + w*32 + row;
        short8 v = {};
        if(s < S_) v = *(const short8*)&qh[((size_t)bh*S_ + s)*HD_ + e8];
        *(short8*)&lP[w*2048 + row*64 + (e8 ^ ((row&7)<<3))] = v;
    }
    short8 qf[2][2];
    #pragma unroll
    for(int qi=0; qi<2; qi++)
        #pragma unroll
        for(int ks=0; ks<2; ks++)
            qf[qi][ks] = *(const short8*)&lP[w*2048 + (qi*16+c)*64 + ((ks*32+g*8) ^ ((c&7)<<3))];

    short8 ones;
    #pragma unroll
    for(int j=0;j<8;j++) ones[j] = (short)0x3F80;

    const int srow = lane>>3;
    const int sw8 = ((lane&7) ^ srow)*8;
    const short* pk0 = kh + ((size_t)bh*SKPAD + w*16 + srow)*64 + sw8;
    const short* pv0 = vt + ((size_t)bh*64 + w*16 + srow)*SKPAD + sw8;

    #pragma unroll
    for(int i=0;i<2;i++){
        gload_lds16(pk0 + i*8*64,    &lK[0][(w*16+i*8)*64]);
        gload_lds16(pv0 + i*8*SKPAD, &lV[0][(w*16+i*8)*64]);
    }

    float m_run[2][4], l_run[2][4];
    f32x4 O[2][4] = {};
    #pragma unroll
    for(int qi=0;qi<2;qi++)
        #pragma unroll
        for(int r=0;r<4;r++){ m_run[qi][r] = -3e38f; l_run[qi][r] = 0.f; }

    int bb = 0;
    for(int kt=0; kt<10; kt++){
        if(kt<9){
            const short* pk = pk0 + (kt+1)*4096;
            const short* pv = pv0 + (kt+1)*64;
            #pragma unroll
            for(int i=0;i<2;i++){
                gload_lds16(pk + i*8*64,    &lK[bb^1][(w*16+i*8)*64]);
                gload_lds16(pv + i*8*SKPAD, &lV[bb^1][(w*16+i*8)*64]);
            }
            asm volatile("s_waitcnt vmcnt(4)" ::: "memory");
        } else {
            asm volatile("s_waitcnt vmcnt(0)" ::: "memory");
        }
        __builtin_amdgcn_s_barrier();
        asm volatile("" ::: "memory");

        const short* LK = lK[bb]; const short* LV = lV[bb];

        float sv[2][4][4];
        #pragma unroll
        for(int nt=0; nt<4; nt++){
            int row = nt*16 + c;
            int rx = (row&7)<<3;
            short8 kf[2];
            kf[0] = *(const short8*)&LK[row*64 + ((g*8) ^ rx)];
            kf[1] = *(const short8*)&LK[row*64 + ((32+g*8) ^ rx)];
            __builtin_amdgcn_s_setprio(1);
            #pragma unroll
            for(int qi=0; qi<2; qi++){
                f32x4 sa = {};
                sa = __builtin_amdgcn_mfma_f32_16x16x32_bf16(qf[qi][0], kf[0], sa, 0,0,0);
                sa = __builtin_amdgcn_mfma_f32_16x16x32_bf16(qf[qi][1], kf[1], sa, 0,0,0);
                #pragma unroll
                for(int r=0;r<4;r++) sv[qi][nt][r] = sa[r]*0.18033688011f;
            }
            __builtin_amdgcn_s_setprio(0);
        }
        if(kt==9){
            #pragma unroll
            for(int nt=0; nt<4; nt++){
                int key = 576 + nt*16 + c;
                if(key >= S_){
                    #pragma unroll
                    for(int qi=0;qi<2;qi++)
                        #pragma unroll
                        for(int r=0;r<4;r++) sv[qi][nt][r] = -3e38f;
                }
            }
        }
        float fac[2][4];
        #pragma unroll
        for(int qi=0; qi<2; qi++)
            #pragma unroll
            for(int r=0;r<4;r++){
                float mx = fmaxf(fmaxf(sv[qi][0][r],sv[qi][1][r]),fmaxf(sv[qi][2][r],sv[qi][3][r]));
                for(int off=1; off<16; off<<=1) mx = fmaxf(mx, __shfl_xor(mx, off));
                float nm = fmaxf(m_run[qi][r], mx);
                fac[qi][r] = __builtin_amdgcn_exp2f(m_run[qi][r] - nm);
                m_run[qi][r] = nm;
            }
        #pragma unroll
        for(int qi=0; qi<2; qi++)
            #pragma unroll
            for(int nt=0; nt<4; nt++)
                #pragma unroll
                for(int r=0;r<4;r++){
                    float p = __builtin_amdgcn_exp2f(sv[qi][nt][r] - m_run[qi][r]);
                    int prow = g*4 + r;
                    lP[w*2048 + qi*1024 + prow*64 + ((nt*16 + c) ^ ((prow&7)<<3))] = (short)f2bf(p);
                }
        short8 pf[2][2];
        #pragma unroll
        for(int qi=0; qi<2; qi++)
            #pragma unroll
            for(int ks=0; ks<2; ks++)
                pf[qi][ks] = *(const short8*)&lP[w*2048 + qi*1024 + c*64 + ((ks*32+g*8) ^ ((c&7)<<3))];
        __builtin_amdgcn_s_setprio(1);
        #pragma unroll
        for(int qi=0; qi<2; qi++){
            f32x4 rs = {};
            rs = __builtin_amdgcn_mfma_f32_16x16x32_bf16(pf[qi][0], ones, rs, 0,0,0);
            rs = __builtin_amdgcn_mfma_f32_16x16x32_bf16(pf[qi][1], ones, rs, 0,0,0);
            #pragma unroll
            for(int r=0;r<4;r++) l_run[qi][r] = l_run[qi][r]*fac[qi][r] + rs[r];
        }
        __builtin_amdgcn_s_setprio(0);
        #pragma unroll
        for(int qi=0; qi<2; qi++)
            #pragma unroll
            for(int nt=0;nt<4;nt++)
                #pragma unroll
                for(int r=0;r<4;r++) O[qi][nt][r] *= fac[qi][r];

        __builtin_amdgcn_s_setprio(1);
        #pragma unroll
        for(int nt=0; nt<4; nt++){
            int vrow = nt*16 + c;
            int rx = (vrow&7)<<3;
            short8 vf[2];
            vf[0] = *(const short8*)&LV[vrow*64 + ((g*8) ^ rx)];
            vf[1] = *(const short8*)&LV[vrow*64 + ((32+g*8) ^ rx)];
            #pragma unroll
            for(int qi=0; qi<2; qi++){
                O[qi][nt] = __builtin_amdgcn_mfma_f32_16x16x32_bf16(pf[qi][0], vf[0], O[qi][nt], 0,0,0);
                O[qi][nt] = __builtin_amdgcn_mfma_f32_16x16x32_bf16(pf[qi][1], vf[1], O[qi][nt], 0,0,0);
            }
        }
        __builtin_amdgcn_s_setprio(0);
        asm volatile("s_waitcnt lgkmcnt(0)" ::: "memory");
        __builtin_amdgcn_s_barrier();
        asm volatile("" ::: "memory");
        bb ^= 1;
    }

    #pragma unroll
    for(int qi=0; qi<2; qi++)
        #pragma unroll
        for(int nt=0; nt<4; nt++)
            #pragma unroll
            for(int r=0;r<4;r++){
                int s = q0 + w*32 + qi*16 + g*4 + r;
                if(s < S_){
                    float val = O[qi][nt][r] / l_run[qi][r];
                    ctx[((size_t)b*S_ + s)*H_ + h*HD_ + nt*16 + c] = (short)f2bf(val);
                }
            }
}

extern "C" void kernel_launch(void* const* d_in, const int* in_sizes, int n_in,
                              void* d_out, int out_size, void* d_ws, size_t ws_size,
                              hipStream_t stream)
{
    const float* hs = (const float*)d_in[0];
    const float* Wq = (const float*)d_in[1];
    const float* bq = (const float*)d_in[2];
    const float* Wk = (const float*)d_in[3];
    const float* bk = (const float*)d_in[4];
    const float* Wv = (const float*)d_in[5];
    const float* bv = (const float*)d_in[6];
    const float* Wo = (const float*)d_in[7];
    const float* bo = (const float*)d_in[8];
    float* out = (float*)d_out;

    char* ws = (char*)d_ws;
    short* abf = (short*)(ws);
    short* ctx = abf;                               // reuse after QKV GEMM
    short* wqt = (short*)(ws + 7274496);
    short* wkt = (short*)(ws + 7274496 + 1179648);
    short* wvt = (short*)(ws + 7274496 + 2*1179648);
    short* wot = (short*)(ws + 7274496 + 3*1179648);
    short* qh  = (short*)(ws + 11993088);
    short* kh  = (short*)(ws + 19083264);
    short* vt  = (short*)(ws + 26947584);
    // total: 34,811,904 B

    k_prep<<<2733, 256, 0, stream>>>(hs, abf, Wq,Wk,Wv,Wo, wqt,wkt,wvt,wot, kh, vt);
    k_qkv<<<171, 512, 0, stream>>>(abf, wqt, bq,bk,bv, qh,kh,vt);
    k_attn<<<dim3(96,5), 256, 0, stream>>>(qh, kh, vt, ctx);
    k_gemm<<<222, 512, 0, stream>>>(ctx, wot, bo, out, 6);
}